// Round 12
// baseline (644.055 us; speedup 1.0000x reference)
//
#include <hip/hip_runtime.h>
#include <math.h>

#define D 64
#define C 2048
#define ROWS (8 * 16384)          // 131072
#define TAU 2e-3f                 // rescore margin (error bound ~8e-5, 25x headroom)

typedef short  bf16x8 __attribute__((ext_vector_type(8)));
typedef float  f32x4  __attribute__((ext_vector_type(4)));
typedef float  v4f    __attribute__((ext_vector_type(4)));

// ---- workspace layout (bytes); harness re-poisons ws each launch -> prep rebuilds all
#define WS_EHI 0                        // bf16 normalized codebook hi  [C*D*2 = 262144]
#define WS_ELO (WS_EHI + C * D * 2)     // bf16 normalized codebook lo  [262144]
#define WS_INV (WS_ELO + C * D * 2)     // f32 1/||e_c||                [8192]
#define WS_CNT (WS_INV + C * 4)         // int worklist count           [16]
#define WS_WL  (WS_CNT + 16)            // int worklist rows            [ROWS*4]

__device__ __forceinline__ unsigned short f2bf(float f) {   // RNE float->bf16
    unsigned u = __float_as_uint(f);
    return (unsigned short)((u + 0x7FFFu + ((u >> 16) & 1u)) >> 16);
}
__device__ __forceinline__ float bf2f(unsigned short h) {
    return __uint_as_float(((unsigned)h) << 16);
}

// ---------------------------------------------------------------------------
// prep: normalize codebook, split to bf16 hi/lo, store invnorm; zero worklist
// (UNCHANGED — validated absmax 0.0)
// ---------------------------------------------------------------------------
__global__ void vq_prep(const float* __restrict__ embed, unsigned char* __restrict__ ws) {
    unsigned short* ehi = (unsigned short*)(ws + WS_EHI);
    unsigned short* elo = (unsigned short*)(ws + WS_ELO);
    float* invn = (float*)(ws + WS_INV);
    int c = blockIdx.x, k = threadIdx.x;
    if (c == 0 && k == 0) *(int*)(ws + WS_CNT) = 0;
    float v = embed[c * D + k];
    float ss = v * v;
    #pragma unroll
    for (int off = 32; off > 0; off >>= 1) ss += __shfl_xor(ss, off, 64);
    float inv = 1.0f / fmaxf(sqrtf(ss), 1e-12f);
    float e = v * inv;
    unsigned short h = f2bf(e);
    ehi[c * D + k] = h;
    elo[c * D + k] = f2bf(e - bf2f(h));
    if (k == 0) invn[c] = inv;
}

// ---------------------------------------------------------------------------
// pass 1: split-bf16 MFMA GEMM + fused argmax(+2nd max) + gather.
// (UNCHANGED — validated absmax 0.0; profile this round)
// ---------------------------------------------------------------------------
#define CHUNK   128
#define NCHUNK  (C / CHUNK)         // 16
#define LDS_ROW 144                 // 128 B data + 16 B pad
#define LDS_ARR (CHUNK * LDS_ROW)   // 18432

__global__ __launch_bounds__(512, 4) void vq_pass1(
        const float* __restrict__ x,
        const float* __restrict__ embed,        // un-normalized, for gather
        unsigned char* __restrict__ ws,
        float* __restrict__ out_q,
        float* __restrict__ out_i) {
    __shared__ unsigned char lds[2 * LDS_ARR];  // 36 KB
    int* cnt = (int*)(ws + WS_CNT);
    int* wl  = (int*)(ws + WS_WL);

    const int tid  = threadIdx.x;
    const int wid  = tid >> 6;
    const int lane = tid & 63;
    const int c15  = lane & 15;     // A row / B col / D col within tile
    const int g    = lane >> 4;     // k-group (A,B), row-group (D)
    const int wrow = blockIdx.x * 256 + wid * 32;

    // ---- A fragments: 32 x-rows -> bf16 hi/lo, resident for whole kernel ----
    bf16x8 Ahi[2][2], Alo[2][2];
    #pragma unroll
    for (int rt = 0; rt < 2; ++rt)
        #pragma unroll
        for (int kt = 0; kt < 2; ++kt) {
            const float* src = x + (size_t)(wrow + rt * 16 + c15) * D + kt * 32 + g * 8;
            v4f f0 = *(const v4f*)src;
            v4f f1 = *(const v4f*)(src + 4);
            float ff[8] = {f0.x, f0.y, f0.z, f0.w, f1.x, f1.y, f1.z, f1.w};
            bf16x8 h, l;
            #pragma unroll
            for (int i = 0; i < 8; ++i) {
                unsigned short hb = f2bf(ff[i]);
                h[i] = (short)hb;
                l[i] = (short)f2bf(ff[i] - bf2f(hb));
            }
            Ahi[rt][kt] = h; Alo[rt][kt] = l;
        }

    float m1[2][4], m2[2][4];
    int   i1[2][4];
    #pragma unroll
    for (int rt = 0; rt < 2; ++rt)
        #pragma unroll
        for (int j = 0; j < 4; ++j) { m1[rt][j] = -INFINITY; m2[rt][j] = -INFINITY; i1[rt][j] = 0; }

    for (int ch = 0; ch < NCHUNK; ++ch) {
        __syncthreads();
        // ---- stage 128 codes (hi+lo) into LDS: 2048 16B units / 512 threads ----
        const int cbase = ch * CHUNK;
        #pragma unroll
        for (int it = 0; it < 4; ++it) {
            int u    = it * 512 + tid;
            int arr  = u >> 10;                 // 0=hi, 1=lo
            int u2   = u & 1023;
            int code = u2 >> 3, k16 = u2 & 7;
            const unsigned short* srcb =
                (const unsigned short*)(ws + (arr ? WS_ELO : WS_EHI)) + (cbase + code) * D + k16 * 8;
            *(bf16x8*)(lds + arr * LDS_ARR + code * LDS_ROW + k16 * 16) = *(const bf16x8*)srcb;
        }
        __syncthreads();

        for (int ct = 0; ct < CHUNK / 16; ++ct) {
            const int boff = (ct * 16 + c15) * LDS_ROW + g * 16;
            bf16x8 Bhi0 = *(const bf16x8*)(lds + boff);
            bf16x8 Bhi1 = *(const bf16x8*)(lds + boff + 64);
            bf16x8 Blo0 = *(const bf16x8*)(lds + LDS_ARR + boff);
            bf16x8 Blo1 = *(const bf16x8*)(lds + LDS_ARR + boff + 64);
            const int ci = cbase + ct * 16 + c15;
            #pragma unroll
            for (int rt = 0; rt < 2; ++rt) {
                f32x4 acc = {0.f, 0.f, 0.f, 0.f};
                acc = __builtin_amdgcn_mfma_f32_16x16x32_bf16(Ahi[rt][0], Bhi0, acc, 0, 0, 0);
                acc = __builtin_amdgcn_mfma_f32_16x16x32_bf16(Ahi[rt][1], Bhi1, acc, 0, 0, 0);
                acc = __builtin_amdgcn_mfma_f32_16x16x32_bf16(Ahi[rt][0], Blo0, acc, 0, 0, 0);
                acc = __builtin_amdgcn_mfma_f32_16x16x32_bf16(Ahi[rt][1], Blo1, acc, 0, 0, 0);
                acc = __builtin_amdgcn_mfma_f32_16x16x32_bf16(Alo[rt][0], Bhi0, acc, 0, 0, 0);
                acc = __builtin_amdgcn_mfma_f32_16x16x32_bf16(Alo[rt][1], Bhi1, acc, 0, 0, 0);
                // fold 4 scores (rows g*4+j, code ci) into running top-2
                #pragma unroll
                for (int j = 0; j < 4; ++j) {
                    float s  = acc[j];
                    bool  gt = s > m1[rt][j];
                    m2[rt][j] = fmaxf(m2[rt][j], fminf(s, m1[rt][j]));
                    i1[rt][j] = gt ? ci : i1[rt][j];
                    m1[rt][j] = gt ? s  : m1[rt][j];
                }
            }
        }
    }

    // ---- 16-lane butterfly reduce (within c15), then cooperative gather ----
    #pragma unroll
    for (int rt = 0; rt < 2; ++rt)
        #pragma unroll
        for (int j = 0; j < 4; ++j) {
            float a1 = m1[rt][j], a2 = m2[rt][j];
            int   ai = i1[rt][j];
            #pragma unroll
            for (int off = 1; off < 16; off <<= 1) {
                float b1 = __shfl_xor(a1, off, 64);
                float b2 = __shfl_xor(a2, off, 64);
                int   bi = __shfl_xor(ai, off, 64);
                bool take = (b1 > a1) || (b1 == a1 && bi < ai);   // first-index tie rule
                a2 = fmaxf(fmaxf(a2, b2), fminf(a1, b1));
                a1 = take ? b1 : a1;
                ai = take ? bi : ai;
            }
            const int row = wrow + rt * 16 + g * 4 + j;
            // 16 lanes write 256 B coalesced: un-normalized codebook row
            v4f e = *(const v4f*)(embed + (size_t)ai * D + c15 * 4);
            *(v4f*)(out_q + (size_t)row * D + c15 * 4) = e;
            if (c15 == 0) {
                out_i[row] = (float)ai;
                if (a1 - a2 < TAU) {                 // ambiguous under split-bf16 error
                    int w = atomicAdd(cnt, 1);
                    if (w < ROWS) wl[w] = row;
                }
            }
        }
}

// ---------------------------------------------------------------------------
// pass 2: exact fp32 rescore, tiled mini-GEMM.
// Round-9 counters: old per-row full-codebook scan = n*512KB L2 traffic
// (n~9000 -> 4.4GB -> 128us L2-bound, VALUBusy 2.8%). New: 32 flagged rows
// per block share one codebook stream -> (n/32)*512KB ~ 143MB. Thread (r,p):
// row r of 32, codes [p*256,(p+1)*256). x rows in LDS, 68-float stride:
// b128 reads hit banks {4r}+4k -> conflict-free broadcast. k-outer/8-code
// inner hoists each x read over 8 codes. Per-code fp32 sum order (k asc,
// x/y/z/w) is bit-identical to the validated round-9 formula.
// ---------------------------------------------------------------------------
#define P2_GRID 512

__global__ __launch_bounds__(256) void vq_pass2(
        const float* __restrict__ x,
        const float* __restrict__ embed,
        unsigned char* __restrict__ ws,
        float* __restrict__ out_q,
        float* __restrict__ out_i) {
    __shared__ float xl[32 * 68];                 // 32 rows, stride 68 floats
    const float* invn = (const float*)(ws + WS_INV);
    int n = *(const int*)(ws + WS_CNT);
    if (n > ROWS) n = ROWS;
    const int* wl = (const int*)(ws + WS_WL);

    const int t = threadIdx.x;
    const int r = t >> 3;          // 0..31: row slot in tile
    const int p = t & 7;           // 0..7 : code partition
    const int ntiles = (n + 31) >> 5;

    for (int tile = blockIdx.x; tile < ntiles; tile += P2_GRID) {
        const int wi    = tile * 32 + r;
        const bool valid = wi < n;
        const int row   = valid ? wl[wi] : 0;

        __syncthreads();                          // protect xl reuse
        {   // stage x row r: 8 lanes x 8 floats
            const float* src = x + (size_t)row * D + p * 8;
            v4f a = *(const v4f*)src;
            v4f b = *(const v4f*)(src + 4);
            *(v4f*)&xl[r * 68 + p * 8]     = a;
            *(v4f*)&xl[r * 68 + p * 8 + 4] = b;
        }
        __syncthreads();

        float m1 = -INFINITY;
        int   i1 = 0;
        const int c0 = p * 256;

        for (int j = 0; j < 32; ++j) {            // 8 codes per step
            const int cb = c0 + j * 8;
            const float* e0 = embed + (size_t)cb * D;
            float s0=0.f,s1=0.f,s2=0.f,s3=0.f,s4=0.f,s5=0.f,s6=0.f,s7=0.f;
            #pragma unroll
            for (int k = 0; k < 16; ++k) {        // k-outer: 1 LDS read / 8 codes
                v4f xv = *(const v4f*)&xl[r * 68 + k * 4];
#define P2_ACC(SS, CI)                                                \
                {                                                     \
                    v4f ev = *(const v4f*)(e0 + (CI) * D + k * 4);    \
                    SS = fmaf(xv.x, ev.x, SS);                        \
                    SS = fmaf(xv.y, ev.y, SS);                        \
                    SS = fmaf(xv.z, ev.z, SS);                        \
                    SS = fmaf(xv.w, ev.w, SS);                        \
                }
                P2_ACC(s0, 0) P2_ACC(s1, 1) P2_ACC(s2, 2) P2_ACC(s3, 3)
                P2_ACC(s4, 4) P2_ACC(s5, 5) P2_ACC(s6, 6) P2_ACC(s7, 7)
#undef P2_ACC
            }
            float sc[8] = {s0, s1, s2, s3, s4, s5, s6, s7};
            #pragma unroll
            for (int q = 0; q < 8; ++q) {         // increasing c, strict '>'
                float s = sc[q] * invn[cb + q];
                if (s > m1) { m1 = s; i1 = cb + q; }
            }
        }

        // merge 8 partitions (xor within the 8-lane row group)
        #pragma unroll
        for (int off = 1; off < 8; off <<= 1) {
            float b1 = __shfl_xor(m1, off, 64);
            int   bi = __shfl_xor(i1, off, 64);
            if (b1 > m1 || (b1 == m1 && bi < i1)) { m1 = b1; i1 = bi; }
        }

        if (valid) {                              // all 8 lanes agree on i1
            const float* eq = embed + (size_t)i1 * D + p * 8;
            float* oq = out_q + (size_t)row * D + p * 8;
            *(v4f*)oq       = *(const v4f*)eq;
            *(v4f*)(oq + 4) = *(const v4f*)(eq + 4);
            if (p == 0) out_i[row] = (float)i1;
        }
    }
}

// ---------------------------------------------------------------------------
extern "C" void kernel_launch(void* const* d_in, const int* in_sizes, int n_in,
                              void* d_out, int out_size, void* d_ws, size_t ws_size,
                              hipStream_t stream) {
    const float* x     = (const float*)d_in[0];   // [8,16384,64] f32
    const float* embed = (const float*)d_in[1];   // [1,2048,64]  f32
    float* out_q = (float*)d_out;                 // 131072*64 floats
    float* out_i = out_q + (size_t)ROWS * D;      // 131072 floats (indices)
    unsigned char* ws = (unsigned char*)d_ws;     // needs ~1.06 MB

    vq_prep <<<C, 64, 0, stream>>>(embed, ws);
    vq_pass1<<<ROWS / 256, 512, 0, stream>>>(x, embed, ws, out_q, out_i);
    vq_pass2<<<P2_GRID, 256, 0, stream>>>(x, embed, ws, out_q, out_i);
}

// Round 14
// 213.180 us; speedup vs baseline: 3.0212x; 3.0212x over previous
//
#include <hip/hip_runtime.h>
#include <math.h>

#define D 64
#define C 2048
#define ROWS (8 * 16384)          // 131072
#define TAU 5e-4f                 // provably safe: wrong-row approx_gap <= 2*eps ~ 3e-4

typedef short  bf16x8 __attribute__((ext_vector_type(8)));
typedef float  f32x4  __attribute__((ext_vector_type(4)));
typedef float  v4f    __attribute__((ext_vector_type(4)));

// ---- workspace layout (bytes); harness re-poisons ws each launch -> prep rebuilds all
#define WS_EHI 0                        // bf16 normalized codebook hi  [C*D*2 = 262144]
#define WS_ELO (WS_EHI + C * D * 2)     // bf16 normalized codebook lo  [262144]
#define WS_INV (WS_ELO + C * D * 2)     // f32 1/||e_c||                [8192]
#define WS_CNT (WS_INV + C * 4)         // int worklist count           [16]
#define WS_WL  (WS_CNT + 16)            // int worklist rows            [ROWS*4]

__device__ __forceinline__ unsigned short f2bf(float f) {   // RNE float->bf16
    unsigned u = __float_as_uint(f);
    return (unsigned short)((u + 0x7FFFu + ((u >> 16) & 1u)) >> 16);
}
__device__ __forceinline__ float bf2f(unsigned short h) {
    return __uint_as_float(((unsigned)h) << 16);
}

// ---------------------------------------------------------------------------
// prep: normalize codebook, split to bf16 hi/lo, store invnorm; zero worklist
// (UNCHANGED — validated absmax 0.0)
// ---------------------------------------------------------------------------
__global__ void vq_prep(const float* __restrict__ embed, unsigned char* __restrict__ ws) {
    unsigned short* ehi = (unsigned short*)(ws + WS_EHI);
    unsigned short* elo = (unsigned short*)(ws + WS_ELO);
    float* invn = (float*)(ws + WS_INV);
    int c = blockIdx.x, k = threadIdx.x;
    if (c == 0 && k == 0) *(int*)(ws + WS_CNT) = 0;
    float v = embed[c * D + k];
    float ss = v * v;
    #pragma unroll
    for (int off = 32; off > 0; off >>= 1) ss += __shfl_xor(ss, off, 64);
    float inv = 1.0f / fmaxf(sqrtf(ss), 1e-12f);
    float e = v * inv;
    unsigned short h = f2bf(e);
    ehi[c * D + k] = h;
    elo[c * D + k] = f2bf(e - bf2f(h));
    if (k == 0) invn[c] = inv;
}

// ---------------------------------------------------------------------------
// pass 1: split-bf16 MFMA GEMM + fused argmax(+2nd max) + gather.
// (UNCHANGED — validated absmax 0.0)
// ---------------------------------------------------------------------------
#define CHUNK   128
#define NCHUNK  (C / CHUNK)         // 16
#define LDS_ROW 144                 // 128 B data + 16 B pad
#define LDS_ARR (CHUNK * LDS_ROW)   // 18432

__global__ __launch_bounds__(512, 4) void vq_pass1(
        const float* __restrict__ x,
        const float* __restrict__ embed,        // un-normalized, for gather
        unsigned char* __restrict__ ws,
        float* __restrict__ out_q,
        float* __restrict__ out_i) {
    __shared__ unsigned char lds[2 * LDS_ARR];  // 36 KB
    int* cnt = (int*)(ws + WS_CNT);
    int* wl  = (int*)(ws + WS_WL);

    const int tid  = threadIdx.x;
    const int wid  = tid >> 6;
    const int lane = tid & 63;
    const int c15  = lane & 15;     // A row / B col / D col within tile
    const int g    = lane >> 4;     // k-group (A,B), row-group (D)
    const int wrow = blockIdx.x * 256 + wid * 32;

    // ---- A fragments: 32 x-rows -> bf16 hi/lo, resident for whole kernel ----
    bf16x8 Ahi[2][2], Alo[2][2];
    #pragma unroll
    for (int rt = 0; rt < 2; ++rt)
        #pragma unroll
        for (int kt = 0; kt < 2; ++kt) {
            const float* src = x + (size_t)(wrow + rt * 16 + c15) * D + kt * 32 + g * 8;
            v4f f0 = *(const v4f*)src;
            v4f f1 = *(const v4f*)(src + 4);
            float ff[8] = {f0.x, f0.y, f0.z, f0.w, f1.x, f1.y, f1.z, f1.w};
            bf16x8 h, l;
            #pragma unroll
            for (int i = 0; i < 8; ++i) {
                unsigned short hb = f2bf(ff[i]);
                h[i] = (short)hb;
                l[i] = (short)f2bf(ff[i] - bf2f(hb));
            }
            Ahi[rt][kt] = h; Alo[rt][kt] = l;
        }

    float m1[2][4], m2[2][4];
    int   i1[2][4];
    #pragma unroll
    for (int rt = 0; rt < 2; ++rt)
        #pragma unroll
        for (int j = 0; j < 4; ++j) { m1[rt][j] = -INFINITY; m2[rt][j] = -INFINITY; i1[rt][j] = 0; }

    for (int ch = 0; ch < NCHUNK; ++ch) {
        __syncthreads();
        // ---- stage 128 codes (hi+lo) into LDS: 2048 16B units / 512 threads ----
        const int cbase = ch * CHUNK;
        #pragma unroll
        for (int it = 0; it < 4; ++it) {
            int u    = it * 512 + tid;
            int arr  = u >> 10;                 // 0=hi, 1=lo
            int u2   = u & 1023;
            int code = u2 >> 3, k16 = u2 & 7;
            const unsigned short* srcb =
                (const unsigned short*)(ws + (arr ? WS_ELO : WS_EHI)) + (cbase + code) * D + k16 * 8;
            *(bf16x8*)(lds + arr * LDS_ARR + code * LDS_ROW + k16 * 16) = *(const bf16x8*)srcb;
        }
        __syncthreads();

        for (int ct = 0; ct < CHUNK / 16; ++ct) {
            const int boff = (ct * 16 + c15) * LDS_ROW + g * 16;
            bf16x8 Bhi0 = *(const bf16x8*)(lds + boff);
            bf16x8 Bhi1 = *(const bf16x8*)(lds + boff + 64);
            bf16x8 Blo0 = *(const bf16x8*)(lds + LDS_ARR + boff);
            bf16x8 Blo1 = *(const bf16x8*)(lds + LDS_ARR + boff + 64);
            const int ci = cbase + ct * 16 + c15;
            #pragma unroll
            for (int rt = 0; rt < 2; ++rt) {
                f32x4 acc = {0.f, 0.f, 0.f, 0.f};
                acc = __builtin_amdgcn_mfma_f32_16x16x32_bf16(Ahi[rt][0], Bhi0, acc, 0, 0, 0);
                acc = __builtin_amdgcn_mfma_f32_16x16x32_bf16(Ahi[rt][1], Bhi1, acc, 0, 0, 0);
                acc = __builtin_amdgcn_mfma_f32_16x16x32_bf16(Ahi[rt][0], Blo0, acc, 0, 0, 0);
                acc = __builtin_amdgcn_mfma_f32_16x16x32_bf16(Ahi[rt][1], Blo1, acc, 0, 0, 0);
                acc = __builtin_amdgcn_mfma_f32_16x16x32_bf16(Alo[rt][0], Bhi0, acc, 0, 0, 0);
                acc = __builtin_amdgcn_mfma_f32_16x16x32_bf16(Alo[rt][1], Bhi1, acc, 0, 0, 0);
                // fold 4 scores (rows g*4+j, code ci) into running top-2
                #pragma unroll
                for (int j = 0; j < 4; ++j) {
                    float s  = acc[j];
                    bool  gt = s > m1[rt][j];
                    m2[rt][j] = fmaxf(m2[rt][j], fminf(s, m1[rt][j]));
                    i1[rt][j] = gt ? ci : i1[rt][j];
                    m1[rt][j] = gt ? s  : m1[rt][j];
                }
            }
        }
    }

    // ---- 16-lane butterfly reduce (within c15), then cooperative gather ----
    #pragma unroll
    for (int rt = 0; rt < 2; ++rt)
        #pragma unroll
        for (int j = 0; j < 4; ++j) {
            float a1 = m1[rt][j], a2 = m2[rt][j];
            int   ai = i1[rt][j];
            #pragma unroll
            for (int off = 1; off < 16; off <<= 1) {
                float b1 = __shfl_xor(a1, off, 64);
                float b2 = __shfl_xor(a2, off, 64);
                int   bi = __shfl_xor(ai, off, 64);
                bool take = (b1 > a1) || (b1 == a1 && bi < ai);   // first-index tie rule
                a2 = fmaxf(fmaxf(a2, b2), fminf(a1, b1));
                a1 = take ? b1 : a1;
                ai = take ? bi : ai;
            }
            const int row = wrow + rt * 16 + g * 4 + j;
            // 16 lanes write 256 B coalesced: un-normalized codebook row
            v4f e = *(const v4f*)(embed + (size_t)ai * D + c15 * 4);
            *(v4f*)(out_q + (size_t)row * D + c15 * 4) = e;
            if (c15 == 0) {
                out_i[row] = (float)ai;
                if (a1 - a2 < TAU) {                 // ambiguous under split-bf16 error
                    int w = atomicAdd(cnt, 1);
                    if (w < ROWS) wl[w] = row;
                }
            }
        }
}

// ---------------------------------------------------------------------------
// pass 2: exact fp32 rescore of worklist rows (round-9 structure: one block
// per flagged row, L2-BW-bound t ~ n*512KB/34.5TB/s. Round-12's tiled
// rewrite was latency-bound at 1.6% occupancy -> 507us; reverted. TAU
// 2e-3->5e-4 cuts n ~9000->~2250 -> ~34us.)
// ---------------------------------------------------------------------------
__global__ __launch_bounds__(256) void vq_pass2(
        const float* __restrict__ x,
        const float* __restrict__ embed,
        unsigned char* __restrict__ ws,
        float* __restrict__ out_q,
        float* __restrict__ out_i) {
    __shared__ float xrow[D];
    __shared__ float sval[256];
    __shared__ int   sidx[256];
    const float* invn = (const float*)(ws + WS_INV);
    int n = *(const int*)(ws + WS_CNT);
    if (n > ROWS) n = ROWS;
    const int* wl = (const int*)(ws + WS_WL);

    for (int w = blockIdx.x; w < n; w += gridDim.x) {
        const int row = wl[w];
        __syncthreads();
        if (threadIdx.x < D) xrow[threadIdx.x] = x[(size_t)row * D + threadIdx.x];
        __syncthreads();
        float best = -INFINITY; int bi = 0;
        for (int c = threadIdx.x; c < C; c += 256) {      // increasing c: first-win via '>'
            float s = 0.f;
            #pragma unroll
            for (int k = 0; k < D; ++k) s = fmaf(xrow[k], embed[c * D + k], s);
            s *= invn[c];
            if (s > best) { best = s; bi = c; }
        }
        sval[threadIdx.x] = best; sidx[threadIdx.x] = bi;
        __syncthreads();
        for (int str = 128; str > 0; str >>= 1) {
            if (threadIdx.x < str) {
                float ov = sval[threadIdx.x + str]; int oi = sidx[threadIdx.x + str];
                if (ov > sval[threadIdx.x] ||
                    (ov == sval[threadIdx.x] && oi < sidx[threadIdx.x])) {
                    sval[threadIdx.x] = ov; sidx[threadIdx.x] = oi;
                }
            }
            __syncthreads();
        }
        const int bidx = sidx[0];
        if (threadIdx.x < D)
            out_q[(size_t)row * D + threadIdx.x] = embed[bidx * D + threadIdx.x];
        if (threadIdx.x == 0) out_i[row] = (float)bidx;
    }
}

// ---------------------------------------------------------------------------
extern "C" void kernel_launch(void* const* d_in, const int* in_sizes, int n_in,
                              void* d_out, int out_size, void* d_ws, size_t ws_size,
                              hipStream_t stream) {
    const float* x     = (const float*)d_in[0];   // [8,16384,64] f32
    const float* embed = (const float*)d_in[1];   // [1,2048,64]  f32
    float* out_q = (float*)d_out;                 // 131072*64 floats
    float* out_i = out_q + (size_t)ROWS * D;      // 131072 floats (indices)
    unsigned char* ws = (unsigned char*)d_ws;     // needs ~1.06 MB

    vq_prep <<<C, 64, 0, stream>>>(embed, ws);
    vq_pass1<<<ROWS / 256, 512, 0, stream>>>(x, embed, ws, out_q, out_i);
    vq_pass2<<<128, 256, 0, stream>>>(x, embed, ws, out_q, out_i);
}